// Round 1
// baseline (8051.044 us; speedup 1.0000x reference)
//
#include <hip/hip_runtime.h>
#include <math.h>

// RewardGuidanceModel: 8-layer Mamba2 stack, B=4096, L=17, fully fused.
// One workgroup (256 thr) per batch element; all activations in LDS/regs.
// Weights transposed into d_ws by prep kernel for coalesced reads.

#define BATCH 4096
#define LSEQ 17
#define DM 128
#define DIN 324
#define DINNER 256
#define DSTATE 32
#define NH 32
#define NL 8
#define DPROJ 608
#define EPSF 1e-5f

// ws layout (floats)
#define OFF_WT 0
#define SZ_WT (NL * DM * DPROJ)            // 622592: in_proj^T  [l][d][j]
#define OFF_OWT (OFF_WT + SZ_WT)
#define SZ_OWT (NL * DINNER * DM)          // 262144: out_proj^T * mixer_norm  [l][in][o]
#define OFF_IWT (OFF_OWT + SZ_OWT)
#define SZ_IWT (DIN * 64)                  // 20736: input_w^T [d][o]
#define OFF_OUTWT (OFF_IWT + SZ_IWT)
#define SZ_OUTWT (DM * DIN)                // 41472: output_w^T [d][o]
#define WS_TOTAL (OFF_OUTWT + SZ_OUTWT)    // 946944 floats = 3.8 MB

// LDS layout (floats). Overlays:
//  G2 (gated products, 256x20) overlays XN (dead after in_proj)
//  STG (prologue staging, 17x324) overlays XSCT/DTT/AT (prologue only)
#define XMAT 0            // 17*128 = 2176   residual stream x
#define XN   2176         // 128*20 = 2560   rmsnorm'd x, transposed+padded [d][t]
#define G2   2176         // 256*20 = 5120   gated y*silu(z), [c][t] padded
#define XSCT 7296         // 256*17 = 4352   post-conv silu'd xs channels [c][t]
#define DTT  11648        // 32*17           dt [h][t]
#define AT   12192        // 32*17           a  [h][t]
#define BC2  12736        // 17*64           B,C compact [t][n] (B: n<32, C: n>=32)
#define RS   13824        // 32              per-row rsqrt scales
#define STG  7296         // 17*324 = 5508   prologue input staging
#define SMEM_TOT 13856    // 54.1 KB -> 2 blocks/CU

__device__ __forceinline__ float siluf(float x) { return x / (1.f + __expf(-x)); }

__global__ void prep_weights(const float* __restrict__ in_proj_w,
                             const float* __restrict__ out_proj_w,
                             const float* __restrict__ mixer_norm_w,
                             const float* __restrict__ input_w,
                             const float* __restrict__ output_w,
                             float* __restrict__ ws) {
    int idx = blockIdx.x * 256 + threadIdx.x;
    if (idx < SZ_WT) {
        int l = idx / (DM * DPROJ);
        int r = idx - l * (DM * DPROJ);
        int d = r / DPROJ, j = r - d * DPROJ;
        ws[OFF_WT + idx] = in_proj_w[(l * DPROJ + j) * DM + d];
    } else if (idx < OFF_IWT) {
        int r2 = idx - OFF_OWT;
        int l = r2 / (DINNER * DM);
        int r = r2 - l * (DINNER * DM);
        int in_ = r / DM, o = r - in_ * DM;
        ws[idx] = out_proj_w[(l * DM + o) * DINNER + in_] * mixer_norm_w[l * DINNER + in_];
    } else if (idx < OFF_OUTWT) {
        int r = idx - OFF_IWT;
        int d = r / 64, o = r - d * 64;
        ws[idx] = input_w[o * DIN + d];
    } else if (idx < WS_TOTAL) {
        int r = idx - OFF_OUTWT;
        int d = r / DIN, o = r - d * DIN;
        ws[idx] = output_w[o * DM + d];
    }
}

__global__ __launch_bounds__(256, 2)
void mamba_all(const float* __restrict__ ini, const float* __restrict__ fut,
               const float* __restrict__ tflag, const float* __restrict__ sval,
               const float* __restrict__ input_b, const float* __restrict__ states_emb,
               const float* __restrict__ time_w, const float* __restrict__ time_b,
               const float* __restrict__ short_w, const float* __restrict__ short_b,
               const float* __restrict__ conv_w, const float* __restrict__ conv_b,
               const float* __restrict__ dt_bias, const float* __restrict__ A_log,
               const float* __restrict__ D_skip, const float* __restrict__ layer_norm_w,
               const float* __restrict__ output_b, const float* __restrict__ ws,
               float* __restrict__ out) {
    __shared__ float S[SMEM_TOT];
    const int tid = threadIdx.x;
    const int b = blockIdx.x;
    const int lane = tid & 63;
    const int wid = tid >> 6;

    const float tf = tflag[b];
    const float sv = sval[b];

    // ---------- prologue: stage raw inputs ----------
    {
        const float* ir = ini + (size_t)b * DIN;
        const float* fr = fut + (size_t)b * 16 * DIN;
        for (int i = tid; i < DIN; i += 256) S[STG + i] = ir[i];
        for (int i = tid; i < 16 * DIN; i += 256) S[STG + DIN + i] = fr[i];
    }
    __syncthreads();
    // input projection (17x64) + embedding into xmat
    {
        const float* iwT = ws + OFF_IWT;
        for (int idx = tid; idx < LSEQ * 64; idx += 256) {
            int t = idx >> 6, o = idx & 63;
            float acc = input_b[o];
            const float* sr = &S[STG + t * DIN];
            for (int d = 0; d < DIN; ++d) acc = fmaf(sr[d], iwT[d * 64 + o], acc);
            S[XMAT + t * DM + 64 + o] = acc;
            S[XMAT + t * DM + o] = states_emb[t * 64 + o];
        }
    }
    __syncthreads();
    // te/se modulation (first halves)
    for (int idx = tid; idx < LSEQ * DM; idx += 256) {
        int d = idx & 127;
        float te0 = fmaf(tf, time_w[d], time_b[d]);
        float te1 = fmaf(tf, time_w[128 + d], time_b[128 + d]);
        float se0 = fmaf(sv, short_w[d], short_b[d]);
        float se1 = fmaf(sv, short_w[128 + d], short_b[128 + d]);
        S[XMAT + idx] = S[XMAT + idx] * te0 * se0 + te1 + se1;
    }

    const int h = tid >> 3;

    // ---------- 8 mamba2 layers ----------
    for (int l = 0; l < NL; ++l) {
        __syncthreads();
        // phase 1: rmsnorm(x) -> XN [d][t] padded stride 20
        {
            const float* lnw = layer_norm_w + l * DM;
            for (int r = wid; r < LSEQ; r += 4) {
                float x0 = S[XMAT + r * DM + lane];
                float x1 = S[XMAT + r * DM + 64 + lane];
                float ss = x0 * x0 + x1 * x1;
                #pragma unroll
                for (int off = 1; off < 64; off <<= 1) ss += __shfl_xor(ss, off, 64);
                float rs = rsqrtf(ss * (1.f / 128.f) + EPSF);
                S[XN + lane * 20 + r] = x0 * rs * lnw[lane];
                S[XN + (64 + lane) * 20 + r] = x1 * rs * lnw[64 + lane];
            }
        }
        __syncthreads();

        // phase 2: in_proj. thread j owns cols {tid, tid+256, tid+512}
        float acc0[17], acc1[17], acc2[17];
        #pragma unroll
        for (int t = 0; t < 17; ++t) { acc0[t] = 0.f; acc1[t] = 0.f; acc2[t] = 0.f; }
        {
            const float* wl = ws + OFF_WT + l * (DM * DPROJ);
            const bool has2 = (tid < 96);
            for (int d = 0; d < DM; ++d) {
                float w0 = wl[d * DPROJ + tid];
                float w1 = wl[d * DPROJ + 256 + tid];
                float w2 = has2 ? wl[d * DPROJ + 512 + tid] : 0.f;
                const float* xr = &S[XN + d * 20];
                float4 q0 = *reinterpret_cast<const float4*>(xr);
                float4 q1 = *reinterpret_cast<const float4*>(xr + 4);
                float4 q2 = *reinterpret_cast<const float4*>(xr + 8);
                float4 q3 = *reinterpret_cast<const float4*>(xr + 12);
                float x16 = xr[16];
                float xv[17] = {q0.x, q0.y, q0.z, q0.w, q1.x, q1.y, q1.z, q1.w,
                                q2.x, q2.y, q2.z, q2.w, q3.x, q3.y, q3.z, q3.w, x16};
                #pragma unroll
                for (int t = 0; t < 17; ++t) {
                    acc0[t] = fmaf(xv[t], w0, acc0[t]);
                    acc1[t] = fmaf(xv[t], w1, acc1[t]);
                    acc2[t] = fmaf(xv[t], w2, acc2[t]);
                }
            }
        }

        // phase 3: conv (register-local) + silu; dt/a for dt-owner threads
        {
            const float* cw = conv_w + l * 320 * 4;
            const float* cb = conv_b + l * 320;
            {   // xs channels 0..255 from acc1 (c = tid)
                float k0 = cw[tid * 4 + 0], k1 = cw[tid * 4 + 1];
                float k2 = cw[tid * 4 + 2], k3 = cw[tid * 4 + 3];
                float bias = cb[tid];
                #pragma unroll
                for (int t = 0; t < 17; ++t) {
                    float s = fmaf(acc1[t], k3, bias);
                    if (t >= 1) s = fmaf(acc1[t - 1], k2, s);
                    if (t >= 2) s = fmaf(acc1[t - 2], k1, s);
                    if (t >= 3) s = fmaf(acc1[t - 3], k0, s);
                    S[XSCT + tid * 17 + t] = siluf(s);
                }
            }
            if (tid < 64) {  // B/C channels 256..319 from acc2
                int c = 256 + tid;
                float k0 = cw[c * 4 + 0], k1 = cw[c * 4 + 1];
                float k2 = cw[c * 4 + 2], k3 = cw[c * 4 + 3];
                float bias = cb[c];
                #pragma unroll
                for (int t = 0; t < 17; ++t) {
                    float s = fmaf(acc2[t], k3, bias);
                    if (t >= 1) s = fmaf(acc2[t - 1], k2, s);
                    if (t >= 2) s = fmaf(acc2[t - 2], k1, s);
                    if (t >= 3) s = fmaf(acc2[t - 3], k0, s);
                    S[BC2 + t * 64 + tid] = siluf(s);
                }
            } else if (tid < 96) {  // dt heads from acc2
                int hh = tid - 64;
                float dtb = dt_bias[l * NH + hh];
                float eA = __expf(A_log[l * NH + hh]);
                #pragma unroll
                for (int t = 0; t < 17; ++t) {
                    float v = acc2[t] + dtb;
                    float dtv = (v > 15.f) ? v : log1pf(__expf(v));
                    S[DTT + hh * 17 + t] = dtv;
                    S[AT + hh * 17 + t] = __expf(-eA * dtv);
                }
            }
        }
        __syncthreads();

        // phase 4: selective scan. thread = (h = tid>>3, p = tid&7), state in regs
        float yreg[17];
        {
            const float Dsk = D_skip[l * NH + h];
            float hst[32];
            #pragma unroll
            for (int n = 0; n < 32; ++n) hst[n] = 0.f;
            #pragma unroll
            for (int t = 0; t < 17; ++t) {
                float xst = S[XSCT + tid * 17 + t];
                float dtv = S[DTT + h * 17 + t];
                float at = S[AT + h * 17 + t];
                float xd = xst * dtv;
                float y = 0.f;
                const float4* bq = reinterpret_cast<const float4*>(&S[BC2 + t * 64]);
                #pragma unroll
                for (int n4 = 0; n4 < 8; ++n4) {
                    float4 bb = bq[n4];
                    float4 cc = bq[8 + n4];
                    hst[4*n4+0] = fmaf(at, hst[4*n4+0], xd * bb.x); y = fmaf(hst[4*n4+0], cc.x, y);
                    hst[4*n4+1] = fmaf(at, hst[4*n4+1], xd * bb.y); y = fmaf(hst[4*n4+1], cc.y, y);
                    hst[4*n4+2] = fmaf(at, hst[4*n4+2], xd * bb.z); y = fmaf(hst[4*n4+2], cc.z, y);
                    hst[4*n4+3] = fmaf(at, hst[4*n4+3], xd * bb.w); y = fmaf(hst[4*n4+3], cc.w, y);
                }
                yreg[t] = fmaf(xst, Dsk, y);
            }
        }
        // phase 5: gating (z = acc0 is register-local!) -> G2 [c][t] stride 20
        #pragma unroll
        for (int t = 0; t < 17; ++t) {
            S[G2 + tid * 20 + t] = yreg[t] * siluf(acc0[t]);
        }
        __syncthreads();
        // phase 6: per-row sumsq -> rowscale
        for (int r = wid; r < LSEQ; r += 4) {
            float ss = 0.f;
            #pragma unroll
            for (int cc = 0; cc < 4; ++cc) {
                float gv = S[G2 + (lane + 64 * cc) * 20 + r];
                ss = fmaf(gv, gv, ss);
            }
            #pragma unroll
            for (int off = 1; off < 64; off <<= 1) ss += __shfl_xor(ss, off, 64);
            if (lane == 0) S[RS + r] = rsqrtf(ss * (1.f / 256.f) + EPSF);
        }
        __syncthreads();
        // phase 7: out_proj (mixer_norm folded into weights, rowscale folded here) + residual
        {
            const int o = tid & 127;
            const int half = tid >> 7;
            const int t0 = half ? 8 : 0;
            float acc[9];
            #pragma unroll
            for (int k = 0; k < 9; ++k) acc[k] = 0.f;
            const float* ow = ws + OFF_OWT + l * (DINNER * DM);
            for (int in = 0; in < DINNER; ++in) {
                float w = ow[in * DM + o];
                const float* gr = &S[G2 + in * 20 + t0];
                float4 g0 = *reinterpret_cast<const float4*>(gr);
                float4 g1 = *reinterpret_cast<const float4*>(gr + 4);
                acc[0] = fmaf(g0.x, w, acc[0]); acc[1] = fmaf(g0.y, w, acc[1]);
                acc[2] = fmaf(g0.z, w, acc[2]); acc[3] = fmaf(g0.w, w, acc[3]);
                acc[4] = fmaf(g1.x, w, acc[4]); acc[5] = fmaf(g1.y, w, acc[5]);
                acc[6] = fmaf(g1.z, w, acc[6]); acc[7] = fmaf(g1.w, w, acc[7]);
                if (half) acc[8] = fmaf(gr[8], w, acc[8]);
            }
            const int nt = half ? 9 : 8;
            for (int k = 0; k < nt; ++k) {
                int t = t0 + k;
                S[XMAT + t * DM + o] += S[RS + t] * acc[k];
            }
        }
    }

    // ---------- epilogue ----------
    __syncthreads();
    for (int idx = tid; idx < LSEQ * DM; idx += 256) {
        int d = idx & 127;
        float te2 = fmaf(tf, time_w[256 + d], time_b[256 + d]);
        float te3 = fmaf(tf, time_w[384 + d], time_b[384 + d]);
        float se2 = fmaf(sv, short_w[256 + d], short_b[256 + d]);
        float se3 = fmaf(sv, short_w[384 + d], short_b[384 + d]);
        S[XN + idx] = S[XMAT + idx] * te2 * se2 + te3 + se3;
    }
    __syncthreads();
    {
        const float* outwT = ws + OFF_OUTWT;
        float* orow = out + (size_t)b * 16 * DIN;
        for (int idx = tid; idx < 16 * DIN; idx += 256) {
            int t1 = idx / DIN;
            int o = idx - t1 * DIN;
            float acc = output_b[o];
            const float* xr = &S[XN + (t1 + 1) * DM];
            for (int d = 0; d < DM; ++d) acc = fmaf(xr[d], outwT[d * DIN + o], acc);
            orow[idx] = acc;
        }
    }
}

extern "C" void kernel_launch(void* const* d_in, const int* in_sizes, int n_in,
                              void* d_out, int out_size, void* d_ws, size_t ws_size,
                              hipStream_t stream) {
    (void)in_sizes; (void)n_in; (void)out_size; (void)ws_size;
    const float* init_states    = (const float*)d_in[0];
    const float* future_states  = (const float*)d_in[1];
    const float* time_flags     = (const float*)d_in[2];
    const float* shortcut_value = (const float*)d_in[3];
    const float* input_w        = (const float*)d_in[4];
    const float* input_b        = (const float*)d_in[5];
    const float* states_emb     = (const float*)d_in[6];
    const float* time_w         = (const float*)d_in[7];
    const float* time_b         = (const float*)d_in[8];
    const float* short_w        = (const float*)d_in[9];
    const float* short_b        = (const float*)d_in[10];
    const float* in_proj_w      = (const float*)d_in[11];
    const float* conv_w         = (const float*)d_in[12];
    const float* conv_b         = (const float*)d_in[13];
    const float* dt_bias        = (const float*)d_in[14];
    const float* A_log          = (const float*)d_in[15];
    const float* D_skip         = (const float*)d_in[16];
    const float* mixer_norm_w   = (const float*)d_in[17];
    const float* out_proj_w     = (const float*)d_in[18];
    const float* layer_norm_w   = (const float*)d_in[19];
    const float* output_w       = (const float*)d_in[20];
    const float* output_b       = (const float*)d_in[21];
    float* ws = (float*)d_ws;
    float* outp = (float*)d_out;

    prep_weights<<<(WS_TOTAL + 255) / 256, 256, 0, stream>>>(
        in_proj_w, out_proj_w, mixer_norm_w, input_w, output_w, ws);
    mamba_all<<<BATCH, 256, 0, stream>>>(
        init_states, future_states, time_flags, shortcut_value,
        input_b, states_emb, time_w, time_b, short_w, short_b,
        conv_w, conv_b, dt_bias, A_log, D_skip, layer_norm_w,
        output_b, ws, outp);
}

// Round 2
// 7820.697 us; speedup vs baseline: 1.0295x; 1.0295x over previous
//
#include <hip/hip_runtime.h>
#include <math.h>

// RewardGuidanceModel: 8-layer Mamba2 stack, B=4096, L=17, fully fused.
// One workgroup (256 thr) per batch element; all activations in LDS/regs.
// R2: scan inputs (XSCT) kept in registers -> LDS 55.4->38.0 KB -> 4 blocks/CU.

#define BATCH 4096
#define LSEQ 17
#define DM 128
#define DIN 324
#define DINNER 256
#define DSTATE 32
#define NH 32
#define NL 8
#define DPROJ 608
#define EPSF 1e-5f

#define OFF_WT 0
#define SZ_WT (NL * DM * DPROJ)
#define OFF_OWT (OFF_WT + SZ_WT)
#define SZ_OWT (NL * DINNER * DM)
#define OFF_IWT (OFF_OWT + SZ_OWT)
#define SZ_IWT (DIN * 64)
#define OFF_OUTWT (OFF_IWT + SZ_IWT)
#define SZ_OUTWT (DM * DIN)
#define WS_TOTAL (OFF_OUTWT + SZ_OUTWT)

#define XMAT 0
#define XN   2176
#define G2   2176
#define DTT  7296
#define AT   7840
#define BC2  8384
#define RS   9472
#define STG  2176
#define SMEM_TOT 9504

__device__ __forceinline__ float siluf(float x) { return x / (1.f + __expf(-x)); }

__global__ void prep_weights(const float* __restrict__ in_proj_w,
                             const float* __restrict__ out_proj_w,
                             const float* __restrict__ mixer_norm_w,
                             const float* __restrict__ input_w,
                             const float* __restrict__ output_w,
                             float* __restrict__ ws) {
    int idx = blockIdx.x * 256 + threadIdx.x;
    if (idx < SZ_WT) {
        int l = idx / (DM * DPROJ);
        int r = idx - l * (DM * DPROJ);
        int d = r / DPROJ, j = r - d * DPROJ;
        ws[OFF_WT + idx] = in_proj_w[(l * DPROJ + j) * DM + d];
    } else if (idx < OFF_IWT) {
        int r2 = idx - OFF_OWT;
        int l = r2 / (DINNER * DM);
        int r = r2 - l * (DINNER * DM);
        int in_ = r / DM, o = r - in_ * DM;
        ws[idx] = out_proj_w[(l * DM + o) * DINNER + in_] * mixer_norm_w[l * DINNER + in_];
    } else if (idx < OFF_OUTWT) {
        int r = idx - OFF_IWT;
        int d = r / 64, o = r - d * 64;
        ws[idx] = input_w[o * DIN + d];
    } else if (idx < WS_TOTAL) {
        int r = idx - OFF_OUTWT;
        int d = r / DIN, o = r - d * DIN;
        ws[idx] = output_w[o * DM + d];
    }
}

__global__ __launch_bounds__(256, 4)
void mamba_all(const float* __restrict__ ini, const float* __restrict__ fut,
               const float* __restrict__ tflag, const float* __restrict__ sval,
               const float* __restrict__ input_b, const float* __restrict__ states_emb,
               const float* __restrict__ time_w, const float* __restrict__ time_b,
               const float* __restrict__ short_w, const float* __restrict__ short_b,
               const float* __restrict__ conv_w, const float* __restrict__ conv_b,
               const float* __restrict__ dt_bias, const float* __restrict__ A_log,
               const float* __restrict__ D_skip, const float* __restrict__ layer_norm_w,
               const float* __restrict__ output_b, const float* __restrict__ ws,
               float* __restrict__ out) {
    __shared__ float S[SMEM_TOT];
    const int tid = threadIdx.x;
    const int b = blockIdx.x;
    const int lane = tid & 63;
    const int wid = tid >> 6;

    const float tf = tflag[b];
    const float sv = sval[b];

    // ---------- prologue: stage raw inputs ----------
    {
        const float* ir = ini + (size_t)b * DIN;
        const float* fr = fut + (size_t)b * 16 * DIN;
        for (int i = tid; i < DIN; i += 256) S[STG + i] = ir[i];
        for (int i = tid; i < 16 * DIN; i += 256) S[STG + DIN + i] = fr[i];
    }
    __syncthreads();
    // input projection (17x64); results in registers, then write after barrier
    float ipacc[5]; float ipemb[5];
    int ipn = 0;
    {
        const float* iwT = ws + OFF_IWT;
        for (int idx = tid; idx < LSEQ * 64; idx += 256) {
            int t = idx >> 6, o = idx & 63;
            float acc = input_b[o];
            const float* sr = &S[STG + t * DIN];
            for (int d = 0; d < DIN; d += 4) {
                float4 sq = *reinterpret_cast<const float4*>(sr + d);
                acc = fmaf(sq.x, iwT[d * 64 + o], acc);
                acc = fmaf(sq.y, iwT[(d + 1) * 64 + o], acc);
                acc = fmaf(sq.z, iwT[(d + 2) * 64 + o], acc);
                acc = fmaf(sq.w, iwT[(d + 3) * 64 + o], acc);
            }
            ipacc[ipn] = acc;
            ipemb[ipn] = states_emb[t * 64 + o];
            ipn++;
        }
    }
    __syncthreads();   // all STG reads done; XMAT region (overlapped by nothing) safe anyway
    {
        int k = 0;
        for (int idx = tid; idx < LSEQ * 64; idx += 256) {
            int t = idx >> 6, o = idx & 63;
            S[XMAT + t * DM + 64 + o] = ipacc[k];
            S[XMAT + t * DM + o] = ipemb[k];
            k++;
        }
    }
    __syncthreads();
    // te/se modulation (first halves)
    for (int idx = tid; idx < LSEQ * DM; idx += 256) {
        int d = idx & 127;
        float te0 = fmaf(tf, time_w[d], time_b[d]);
        float te1 = fmaf(tf, time_w[128 + d], time_b[128 + d]);
        float se0 = fmaf(sv, short_w[d], short_b[d]);
        float se1 = fmaf(sv, short_w[128 + d], short_b[128 + d]);
        S[XMAT + idx] = S[XMAT + idx] * te0 * se0 + te1 + se1;
    }

    const int h = tid >> 3;

    // ---------- 8 mamba2 layers ----------
    for (int l = 0; l < NL; ++l) {
        __syncthreads();
        // phase 1: rmsnorm(x) -> XN [d][t] padded stride 20
        {
            const float* lnw = layer_norm_w + l * DM;
            for (int r = wid; r < LSEQ; r += 4) {
                float x0 = S[XMAT + r * DM + lane];
                float x1 = S[XMAT + r * DM + 64 + lane];
                float ss = x0 * x0 + x1 * x1;
                #pragma unroll
                for (int off = 1; off < 64; off <<= 1) ss += __shfl_xor(ss, off, 64);
                float rs = rsqrtf(ss * (1.f / 128.f) + EPSF);
                S[XN + lane * 20 + r] = x0 * rs * lnw[lane];
                S[XN + (64 + lane) * 20 + r] = x1 * rs * lnw[64 + lane];
            }
        }
        __syncthreads();

        // phase 2: in_proj. thread j owns cols {tid, tid+256, tid+512(tid<96)}
        float acc0[17], acc1[17], acc2[17];
        #pragma unroll
        for (int t = 0; t < 17; ++t) { acc0[t] = 0.f; acc1[t] = 0.f; acc2[t] = 0.f; }
        {
            const float* wl = ws + OFF_WT + l * (DM * DPROJ);
            const bool has2 = (tid < 96);
            const bool anyw2 = (tid < 128);   // wave-uniform for waves 0,2,3
            for (int d = 0; d < DM; ++d) {
                float w0 = wl[d * DPROJ + tid];
                float w1 = wl[d * DPROJ + 256 + tid];
                const float* xr = &S[XN + d * 20];
                float4 q0 = *reinterpret_cast<const float4*>(xr);
                float4 q1 = *reinterpret_cast<const float4*>(xr + 4);
                float4 q2 = *reinterpret_cast<const float4*>(xr + 8);
                float4 q3 = *reinterpret_cast<const float4*>(xr + 12);
                float x16 = xr[16];
                float xv[17] = {q0.x, q0.y, q0.z, q0.w, q1.x, q1.y, q1.z, q1.w,
                                q2.x, q2.y, q2.z, q2.w, q3.x, q3.y, q3.z, q3.w, x16};
                #pragma unroll
                for (int t = 0; t < 17; ++t) {
                    acc0[t] = fmaf(xv[t], w0, acc0[t]);
                    acc1[t] = fmaf(xv[t], w1, acc1[t]);
                }
                if (anyw2) {
                    float w2 = has2 ? wl[d * DPROJ + 512 + tid] : 0.f;
                    #pragma unroll
                    for (int t = 0; t < 17; ++t) acc2[t] = fmaf(xv[t], w2, acc2[t]);
                }
            }
        }

        // phase 3: conv (register-local) + silu; xs stays in registers
        float xst[17];
        {
            const float* cw = conv_w + l * 320 * 4;
            const float* cb = conv_b + l * 320;
            {
                float k0 = cw[tid * 4 + 0], k1 = cw[tid * 4 + 1];
                float k2 = cw[tid * 4 + 2], k3 = cw[tid * 4 + 3];
                float bias = cb[tid];
                #pragma unroll
                for (int t = 0; t < 17; ++t) {
                    float s = fmaf(acc1[t], k3, bias);
                    if (t >= 1) s = fmaf(acc1[t - 1], k2, s);
                    if (t >= 2) s = fmaf(acc1[t - 2], k1, s);
                    if (t >= 3) s = fmaf(acc1[t - 3], k0, s);
                    xst[t] = siluf(s);
                }
            }
            if (tid < 64) {
                int c = 256 + tid;
                float k0 = cw[c * 4 + 0], k1 = cw[c * 4 + 1];
                float k2 = cw[c * 4 + 2], k3 = cw[c * 4 + 3];
                float bias = cb[c];
                #pragma unroll
                for (int t = 0; t < 17; ++t) {
                    float s = fmaf(acc2[t], k3, bias);
                    if (t >= 1) s = fmaf(acc2[t - 1], k2, s);
                    if (t >= 2) s = fmaf(acc2[t - 2], k1, s);
                    if (t >= 3) s = fmaf(acc2[t - 3], k0, s);
                    S[BC2 + t * 64 + tid] = siluf(s);
                }
            } else if (tid < 96) {
                int hh = tid - 64;
                float dtb = dt_bias[l * NH + hh];
                float eA = __expf(A_log[l * NH + hh]);
                #pragma unroll
                for (int t = 0; t < 17; ++t) {
                    float v = acc2[t] + dtb;
                    float dtv = (v > 15.f) ? v : log1pf(__expf(v));
                    S[DTT + hh * 17 + t] = dtv;
                    S[AT + hh * 17 + t] = __expf(-eA * dtv);
                }
            }
        }
        __syncthreads();

        // phase 4: selective scan. thread = (h, p); state in regs; yreg overwrites xst
        {
            const float Dsk = D_skip[l * NH + h];
            float hst[32];
            #pragma unroll
            for (int n = 0; n < 32; ++n) hst[n] = 0.f;
            #pragma unroll
            for (int t = 0; t < 17; ++t) {
                float xs_t = xst[t];
                float dtv = S[DTT + h * 17 + t];
                float at = S[AT + h * 17 + t];
                float xd = xs_t * dtv;
                float y = 0.f;
                const float4* bq = reinterpret_cast<const float4*>(&S[BC2 + t * 64]);
                #pragma unroll
                for (int n4 = 0; n4 < 8; ++n4) {
                    float4 bb = bq[n4];
                    float4 cc = bq[8 + n4];
                    hst[4*n4+0] = fmaf(at, hst[4*n4+0], xd * bb.x); y = fmaf(hst[4*n4+0], cc.x, y);
                    hst[4*n4+1] = fmaf(at, hst[4*n4+1], xd * bb.y); y = fmaf(hst[4*n4+1], cc.y, y);
                    hst[4*n4+2] = fmaf(at, hst[4*n4+2], xd * bb.z); y = fmaf(hst[4*n4+2], cc.z, y);
                    hst[4*n4+3] = fmaf(at, hst[4*n4+3], xd * bb.w); y = fmaf(hst[4*n4+3], cc.w, y);
                }
                xst[t] = fmaf(xs_t, Dsk, y);
            }
        }
        // phase 5: gating (z = acc0 register-local) -> G2 [c][t] stride 20
        #pragma unroll
        for (int t = 0; t < 17; ++t) {
            S[G2 + tid * 20 + t] = xst[t] * siluf(acc0[t]);
        }
        __syncthreads();
        // phase 6: per-row sumsq -> rowscale
        for (int r = wid; r < LSEQ; r += 4) {
            float ss = 0.f;
            #pragma unroll
            for (int cc = 0; cc < 4; ++cc) {
                float gv = S[G2 + (lane + 64 * cc) * 20 + r];
                ss = fmaf(gv, gv, ss);
            }
            #pragma unroll
            for (int off = 1; off < 64; off <<= 1) ss += __shfl_xor(ss, off, 64);
            if (lane == 0) S[RS + r] = rsqrtf(ss * (1.f / 256.f) + EPSF);
        }
        __syncthreads();
        // phase 7: out_proj + residual
        {
            const int o = tid & 127;
            const int half = tid >> 7;
            const int t0 = half ? 8 : 0;
            float acc[9];
            #pragma unroll
            for (int k = 0; k < 9; ++k) acc[k] = 0.f;
            const float* ow = ws + OFF_OWT + l * (DINNER * DM);
            for (int in = 0; in < DINNER; ++in) {
                float w = ow[in * DM + o];
                const float* gr = &S[G2 + in * 20 + t0];
                float4 g0 = *reinterpret_cast<const float4*>(gr);
                float4 g1 = *reinterpret_cast<const float4*>(gr + 4);
                acc[0] = fmaf(g0.x, w, acc[0]); acc[1] = fmaf(g0.y, w, acc[1]);
                acc[2] = fmaf(g0.z, w, acc[2]); acc[3] = fmaf(g0.w, w, acc[3]);
                acc[4] = fmaf(g1.x, w, acc[4]); acc[5] = fmaf(g1.y, w, acc[5]);
                acc[6] = fmaf(g1.z, w, acc[6]); acc[7] = fmaf(g1.w, w, acc[7]);
                if (half) acc[8] = fmaf(gr[8], w, acc[8]);
            }
            const int nt = half ? 9 : 8;
            for (int k = 0; k < nt; ++k) {
                int t = t0 + k;
                S[XMAT + t * DM + o] += S[RS + t] * acc[k];
            }
        }
    }

    // ---------- epilogue ----------
    __syncthreads();
    for (int idx = tid; idx < LSEQ * DM; idx += 256) {
        int d = idx & 127;
        float te2 = fmaf(tf, time_w[256 + d], time_b[256 + d]);
        float te3 = fmaf(tf, time_w[384 + d], time_b[384 + d]);
        float se2 = fmaf(sv, short_w[256 + d], short_b[256 + d]);
        float se3 = fmaf(sv, short_w[384 + d], short_b[384 + d]);
        S[XN + idx] = S[XMAT + idx] * te2 * se2 + te3 + se3;
    }
    __syncthreads();
    {
        const float* outwT = ws + OFF_OUTWT;
        float* orow = out + (size_t)b * 16 * DIN;
        for (int idx = tid; idx < 16 * DIN; idx += 256) {
            int t1 = idx / DIN;
            int o = idx - t1 * DIN;
            float acc = output_b[o];
            const float* xr = &S[XN + (t1 + 1) * DM];
            for (int d = 0; d < DM; d += 4) {
                float4 xq = *reinterpret_cast<const float4*>(xr + d);
                acc = fmaf(xq.x, outwT[d * DIN + o], acc);
                acc = fmaf(xq.y, outwT[(d + 1) * DIN + o], acc);
                acc = fmaf(xq.z, outwT[(d + 2) * DIN + o], acc);
                acc = fmaf(xq.w, outwT[(d + 3) * DIN + o], acc);
            }
            orow[idx] = acc;
        }
    }
}

extern "C" void kernel_launch(void* const* d_in, const int* in_sizes, int n_in,
                              void* d_out, int out_size, void* d_ws, size_t ws_size,
                              hipStream_t stream) {
    (void)in_sizes; (void)n_in; (void)out_size; (void)ws_size;
    const float* init_states    = (const float*)d_in[0];
    const float* future_states  = (const float*)d_in[1];
    const float* time_flags     = (const float*)d_in[2];
    const float* shortcut_value = (const float*)d_in[3];
    const float* input_w        = (const float*)d_in[4];
    const float* input_b        = (const float*)d_in[5];
    const float* states_emb     = (const float*)d_in[6];
    const float* time_w         = (const float*)d_in[7];
    const float* time_b         = (const float*)d_in[8];
    const float* short_w        = (const float*)d_in[9];
    const float* short_b        = (const float*)d_in[10];
    const float* in_proj_w      = (const float*)d_in[11];
    const float* conv_w         = (const float*)d_in[12];
    const float* conv_b         = (const float*)d_in[13];
    const float* dt_bias        = (const float*)d_in[14];
    const float* A_log          = (const float*)d_in[15];
    const float* D_skip         = (const float*)d_in[16];
    const float* mixer_norm_w   = (const float*)d_in[17];
    const float* out_proj_w     = (const float*)d_in[18];
    const float* layer_norm_w   = (const float*)d_in[19];
    const float* output_w       = (const float*)d_in[20];
    const float* output_b       = (const float*)d_in[21];
    float* ws = (float*)d_ws;
    float* outp = (float*)d_out;

    prep_weights<<<(WS_TOTAL + 255) / 256, 256, 0, stream>>>(
        in_proj_w, out_proj_w, mixer_norm_w, input_w, output_w, ws);
    mamba_all<<<BATCH, 256, 0, stream>>>(
        init_states, future_states, time_flags, shortcut_value,
        input_b, states_emb, time_w, time_b, short_w, short_b,
        conv_w, conv_b, dt_bias, A_log, D_skip, layer_norm_w,
        output_b, ws, outp);
}

// Round 3
// 7640.108 us; speedup vs baseline: 1.0538x; 1.0236x over previous
//
#include <hip/hip_runtime.h>
#include <math.h>

// RewardGuidanceModel: 8-layer Mamba2 stack, B=4096, L=17, fully fused.
// One workgroup (256 thr) per batch element; all activations in LDS/regs.
// R3: no-spill register budget. launch_bounds(256,3) (cap 168 VGPR; R2's
// (256,4) forced 64 VGPR -> 10 GB scratch spill traffic). Two-pass in_proj
// + early z-gating store cut peak pressure to ~100 so allocator can land
// <=128 VGPR -> 4 blocks/CU at 38.4 KB LDS.

#define BATCH 4096
#define LSEQ 17
#define DM 128
#define DIN 324
#define DINNER 256
#define DSTATE 32
#define NH 32
#define NL 8
#define DPROJ 608
#define EPSF 1e-5f

#define OFF_WT 0
#define SZ_WT (NL * DM * DPROJ)
#define OFF_OWT (OFF_WT + SZ_WT)
#define SZ_OWT (NL * DINNER * DM)
#define OFF_IWT (OFF_OWT + SZ_OWT)
#define SZ_IWT (DIN * 64)
#define OFF_OUTWT (OFF_IWT + SZ_IWT)
#define SZ_OUTWT (DM * DIN)
#define WS_TOTAL (OFF_OUTWT + SZ_OUTWT)

#define XMAT 0
#define XN   2176
#define G2   2176
#define DTT  7296
#define AT   7840
#define BC2  8384
#define RS   9472
#define STG  2176
#define SMEM_TOT 9504

__device__ __forceinline__ float siluf(float x) { return x / (1.f + __expf(-x)); }

__global__ void prep_weights(const float* __restrict__ in_proj_w,
                             const float* __restrict__ out_proj_w,
                             const float* __restrict__ mixer_norm_w,
                             const float* __restrict__ input_w,
                             const float* __restrict__ output_w,
                             float* __restrict__ ws) {
    int idx = blockIdx.x * 256 + threadIdx.x;
    if (idx < SZ_WT) {
        int l = idx / (DM * DPROJ);
        int r = idx - l * (DM * DPROJ);
        int d = r / DPROJ, j = r - d * DPROJ;
        ws[OFF_WT + idx] = in_proj_w[(l * DPROJ + j) * DM + d];
    } else if (idx < OFF_IWT) {
        int r2 = idx - OFF_OWT;
        int l = r2 / (DINNER * DM);
        int r = r2 - l * (DINNER * DM);
        int in_ = r / DM, o = r - in_ * DM;
        ws[idx] = out_proj_w[(l * DM + o) * DINNER + in_] * mixer_norm_w[l * DINNER + in_];
    } else if (idx < OFF_OUTWT) {
        int r = idx - OFF_IWT;
        int d = r / 64, o = r - d * 64;
        ws[idx] = input_w[o * DIN + d];
    } else if (idx < WS_TOTAL) {
        int r = idx - OFF_OUTWT;
        int d = r / DIN, o = r - d * DIN;
        ws[idx] = output_w[o * DM + d];
    }
}

__global__ __launch_bounds__(256, 3)
void mamba_all(const float* __restrict__ ini, const float* __restrict__ fut,
               const float* __restrict__ tflag, const float* __restrict__ sval,
               const float* __restrict__ input_b, const float* __restrict__ states_emb,
               const float* __restrict__ time_w, const float* __restrict__ time_b,
               const float* __restrict__ short_w, const float* __restrict__ short_b,
               const float* __restrict__ conv_w, const float* __restrict__ conv_b,
               const float* __restrict__ dt_bias, const float* __restrict__ A_log,
               const float* __restrict__ D_skip, const float* __restrict__ layer_norm_w,
               const float* __restrict__ output_b, const float* __restrict__ ws,
               float* __restrict__ out) {
    __shared__ float S[SMEM_TOT];
    const int tid = threadIdx.x;
    const int b = blockIdx.x;
    const int lane = tid & 63;
    const int wid = tid >> 6;

    const float tf = tflag[b];
    const float sv = sval[b];

    // ---------- prologue: stage raw inputs ----------
    {
        const float* ir = ini + (size_t)b * DIN;
        const float* fr = fut + (size_t)b * 16 * DIN;
        for (int i = tid; i < DIN; i += 256) S[STG + i] = ir[i];
        for (int i = tid; i < 16 * DIN; i += 256) S[STG + DIN + i] = fr[i];
    }
    __syncthreads();
    // input projection (17x64); results in registers, written after barrier
    float ipacc[5]; float ipemb[5];
    int ipn = 0;
    {
        const float* iwT = ws + OFF_IWT;
        for (int idx = tid; idx < LSEQ * 64; idx += 256) {
            int t = idx >> 6, o = idx & 63;
            float acc = input_b[o];
            const float* sr = &S[STG + t * DIN];
            for (int d = 0; d < DIN; d += 4) {
                float4 sq = *reinterpret_cast<const float4*>(sr + d);
                acc = fmaf(sq.x, iwT[d * 64 + o], acc);
                acc = fmaf(sq.y, iwT[(d + 1) * 64 + o], acc);
                acc = fmaf(sq.z, iwT[(d + 2) * 64 + o], acc);
                acc = fmaf(sq.w, iwT[(d + 3) * 64 + o], acc);
            }
            ipacc[ipn] = acc;
            ipemb[ipn] = states_emb[t * 64 + o];
            ipn++;
        }
    }
    __syncthreads();
    {
        int k = 0;
        for (int idx = tid; idx < LSEQ * 64; idx += 256) {
            int t = idx >> 6, o = idx & 63;
            S[XMAT + t * DM + 64 + o] = ipacc[k];
            S[XMAT + t * DM + o] = ipemb[k];
            k++;
        }
    }
    __syncthreads();
    // te/se modulation (first halves)
    for (int idx = tid; idx < LSEQ * DM; idx += 256) {
        int d = idx & 127;
        float te0 = fmaf(tf, time_w[d], time_b[d]);
        float te1 = fmaf(tf, time_w[128 + d], time_b[128 + d]);
        float se0 = fmaf(sv, short_w[d], short_b[d]);
        float se1 = fmaf(sv, short_w[128 + d], short_b[128 + d]);
        S[XMAT + idx] = S[XMAT + idx] * te0 * se0 + te1 + se1;
    }

    const int h = tid >> 3;

    // ---------- 8 mamba2 layers ----------
    for (int l = 0; l < NL; ++l) {
        __syncthreads();
        // phase 1: rmsnorm(x) -> XN [d][t] padded stride 20
        {
            const float* lnw = layer_norm_w + l * DM;
            for (int r = wid; r < LSEQ; r += 4) {
                float x0 = S[XMAT + r * DM + lane];
                float x1 = S[XMAT + r * DM + 64 + lane];
                float ss = x0 * x0 + x1 * x1;
                #pragma unroll
                for (int off = 1; off < 64; off <<= 1) ss += __shfl_xor(ss, off, 64);
                float rs = rsqrtf(ss * (1.f / 128.f) + EPSF);
                S[XN + lane * 20 + r] = x0 * rs * lnw[lane];
                S[XN + (64 + lane) * 20 + r] = x1 * rs * lnw[64 + lane];
            }
        }
        __syncthreads();

        // phase 2, pass A: z (acc0) and xs (acc1) columns, all threads
        float acc0[17], acc1[17];
        #pragma unroll
        for (int t = 0; t < 17; ++t) { acc0[t] = 0.f; acc1[t] = 0.f; }
        {
            const float* wl = ws + OFF_WT + l * (DM * DPROJ);
            for (int d = 0; d < DM; ++d) {
                float w0 = wl[d * DPROJ + tid];
                float w1 = wl[d * DPROJ + 256 + tid];
                const float* xr = &S[XN + d * 20];
                float4 q0 = *reinterpret_cast<const float4*>(xr);
                float4 q1 = *reinterpret_cast<const float4*>(xr + 4);
                float4 q2 = *reinterpret_cast<const float4*>(xr + 8);
                float4 q3 = *reinterpret_cast<const float4*>(xr + 12);
                float x16 = xr[16];
                float xv[17] = {q0.x, q0.y, q0.z, q0.w, q1.x, q1.y, q1.z, q1.w,
                                q2.x, q2.y, q2.z, q2.w, q3.x, q3.y, q3.z, q3.w, x16};
                #pragma unroll
                for (int t = 0; t < 17; ++t) {
                    acc0[t] = fmaf(xv[t], w0, acc0[t]);
                    acc1[t] = fmaf(xv[t], w1, acc1[t]);
                }
            }
        }
        // phase 2, pass B: B/C/dt columns (acc2), waves 0-1 only (wave-uniform skip)
        float acc2[17];
        #pragma unroll
        for (int t = 0; t < 17; ++t) acc2[t] = 0.f;
        if (tid < 128) {
            const float* wl = ws + OFF_WT + l * (DM * DPROJ);
            const bool has2 = (tid < 96);
            for (int d = 0; d < DM; ++d) {
                float w2 = has2 ? wl[d * DPROJ + 512 + tid] : 0.f;
                const float* xr = &S[XN + d * 20];
                float4 q0 = *reinterpret_cast<const float4*>(xr);
                float4 q1 = *reinterpret_cast<const float4*>(xr + 4);
                float4 q2 = *reinterpret_cast<const float4*>(xr + 8);
                float4 q3 = *reinterpret_cast<const float4*>(xr + 12);
                float x16 = xr[16];
                float xv[17] = {q0.x, q0.y, q0.z, q0.w, q1.x, q1.y, q1.z, q1.w,
                                q2.x, q2.y, q2.z, q2.w, q3.x, q3.y, q3.z, q3.w, x16};
                #pragma unroll
                for (int t = 0; t < 17; ++t) acc2[t] = fmaf(xv[t], w2, acc2[t]);
            }
        }

        // phase 3: conv (register-local) + silu; xs stays in registers
        float xst[17];
        {
            const float* cw = conv_w + l * 320 * 4;
            const float* cb = conv_b + l * 320;
            {
                float k0 = cw[tid * 4 + 0], k1 = cw[tid * 4 + 1];
                float k2 = cw[tid * 4 + 2], k3 = cw[tid * 4 + 3];
                float bias = cb[tid];
                #pragma unroll
                for (int t = 0; t < 17; ++t) {
                    float s = fmaf(acc1[t], k3, bias);
                    if (t >= 1) s = fmaf(acc1[t - 1], k2, s);
                    if (t >= 2) s = fmaf(acc1[t - 2], k1, s);
                    if (t >= 3) s = fmaf(acc1[t - 3], k0, s);
                    xst[t] = siluf(s);
                }
            }
            if (tid < 64) {
                int c = 256 + tid;
                float k0 = cw[c * 4 + 0], k1 = cw[c * 4 + 1];
                float k2 = cw[c * 4 + 2], k3 = cw[c * 4 + 3];
                float bias = cb[c];
                #pragma unroll
                for (int t = 0; t < 17; ++t) {
                    float s = fmaf(acc2[t], k3, bias);
                    if (t >= 1) s = fmaf(acc2[t - 1], k2, s);
                    if (t >= 2) s = fmaf(acc2[t - 2], k1, s);
                    if (t >= 3) s = fmaf(acc2[t - 3], k0, s);
                    S[BC2 + t * 64 + tid] = siluf(s);
                }
            } else if (tid < 96) {
                int hh = tid - 64;
                float dtb = dt_bias[l * NH + hh];
                float eA = __expf(A_log[l * NH + hh]);
                #pragma unroll
                for (int t = 0; t < 17; ++t) {
                    float v = acc2[t] + dtb;
                    float dtv = (v > 15.f) ? v : log1pf(__expf(v));
                    S[DTT + hh * 17 + t] = dtv;
                    S[AT + hh * 17 + t] = __expf(-eA * dtv);
                }
            }
        }
        __syncthreads();

        // early gating store: G2 = silu(z). Frees acc0 before the scan.
        // (XN reads all completed before the barrier above; G2 overlays XN.)
        #pragma unroll
        for (int t = 0; t < 17; ++t) {
            S[G2 + tid * 20 + t] = siluf(acc0[t]);
        }

        // phase 4: selective scan. thread = (h, p); state in regs; y overwrites xst
        {
            const float Dsk = D_skip[l * NH + h];
            float hst[32];
            #pragma unroll
            for (int n = 0; n < 32; ++n) hst[n] = 0.f;
            #pragma unroll
            for (int t = 0; t < 17; ++t) {
                float xs_t = xst[t];
                float dtv = S[DTT + h * 17 + t];
                float at = S[AT + h * 17 + t];
                float xd = xs_t * dtv;
                float y = 0.f;
                const float4* bq = reinterpret_cast<const float4*>(&S[BC2 + t * 64]);
                #pragma unroll
                for (int n4 = 0; n4 < 8; ++n4) {
                    float4 bb = bq[n4];
                    float4 cc = bq[8 + n4];
                    hst[4*n4+0] = fmaf(at, hst[4*n4+0], xd * bb.x); y = fmaf(hst[4*n4+0], cc.x, y);
                    hst[4*n4+1] = fmaf(at, hst[4*n4+1], xd * bb.y); y = fmaf(hst[4*n4+1], cc.y, y);
                    hst[4*n4+2] = fmaf(at, hst[4*n4+2], xd * bb.z); y = fmaf(hst[4*n4+2], cc.z, y);
                    hst[4*n4+3] = fmaf(at, hst[4*n4+3], xd * bb.w); y = fmaf(hst[4*n4+3], cc.w, y);
                }
                xst[t] = fmaf(xs_t, Dsk, y);
            }
        }
        // phase 5: multiply gate in place: G2 *= y  (own row only, no race)
        #pragma unroll
        for (int t = 0; t < 17; ++t) {
            S[G2 + tid * 20 + t] *= xst[t];
        }
        __syncthreads();
        // phase 6: per-row sumsq -> rowscale
        for (int r = wid; r < LSEQ; r += 4) {
            float ss = 0.f;
            #pragma unroll
            for (int cc = 0; cc < 4; ++cc) {
                float gv = S[G2 + (lane + 64 * cc) * 20 + r];
                ss = fmaf(gv, gv, ss);
            }
            #pragma unroll
            for (int off = 1; off < 64; off <<= 1) ss += __shfl_xor(ss, off, 64);
            if (lane == 0) S[RS + r] = rsqrtf(ss * (1.f / 256.f) + EPSF);
        }
        __syncthreads();
        // phase 7: out_proj + residual
        {
            const int o = tid & 127;
            const int half = tid >> 7;
            const int t0 = half ? 8 : 0;
            float acc[9];
            #pragma unroll
            for (int k = 0; k < 9; ++k) acc[k] = 0.f;
            const float* ow = ws + OFF_OWT + l * (DINNER * DM);
            for (int in = 0; in < DINNER; ++in) {
                float w = ow[in * DM + o];
                const float* gr = &S[G2 + in * 20 + t0];
                float4 g0 = *reinterpret_cast<const float4*>(gr);
                float4 g1 = *reinterpret_cast<const float4*>(gr + 4);
                acc[0] = fmaf(g0.x, w, acc[0]); acc[1] = fmaf(g0.y, w, acc[1]);
                acc[2] = fmaf(g0.z, w, acc[2]); acc[3] = fmaf(g0.w, w, acc[3]);
                acc[4] = fmaf(g1.x, w, acc[4]); acc[5] = fmaf(g1.y, w, acc[5]);
                acc[6] = fmaf(g1.z, w, acc[6]); acc[7] = fmaf(g1.w, w, acc[7]);
                if (half) acc[8] = fmaf(gr[8], w, acc[8]);
            }
            const int nt = half ? 9 : 8;
            for (int k = 0; k < nt; ++k) {
                int t = t0 + k;
                S[XMAT + t * DM + o] += S[RS + t] * acc[k];
            }
        }
    }

    // ---------- epilogue ----------
    __syncthreads();
    for (int idx = tid; idx < LSEQ * DM; idx += 256) {
        int d = idx & 127;
        float te2 = fmaf(tf, time_w[256 + d], time_b[256 + d]);
        float te3 = fmaf(tf, time_w[384 + d], time_b[384 + d]);
        float se2 = fmaf(sv, short_w[256 + d], short_b[256 + d]);
        float se3 = fmaf(sv, short_w[384 + d], short_b[384 + d]);
        S[XN + idx] = S[XMAT + idx] * te2 * se2 + te3 + se3;
    }
    __syncthreads();
    {
        const float* outwT = ws + OFF_OUTWT;
        float* orow = out + (size_t)b * 16 * DIN;
        for (int idx = tid; idx < 16 * DIN; idx += 256) {
            int t1 = idx / DIN;
            int o = idx - t1 * DIN;
            float acc = output_b[o];
            const float* xr = &S[XN + (t1 + 1) * DM];
            for (int d = 0; d < DM; d += 4) {
                float4 xq = *reinterpret_cast<const float4*>(xr + d);
                acc = fmaf(xq.x, outwT[d * DIN + o], acc);
                acc = fmaf(xq.y, outwT[(d + 1) * DIN + o], acc);
                acc = fmaf(xq.z, outwT[(d + 2) * DIN + o], acc);
                acc = fmaf(xq.w, outwT[(d + 3) * DIN + o], acc);
            }
            orow[idx] = acc;
        }
    }
}

extern "C" void kernel_launch(void* const* d_in, const int* in_sizes, int n_in,
                              void* d_out, int out_size, void* d_ws, size_t ws_size,
                              hipStream_t stream) {
    (void)in_sizes; (void)n_in; (void)out_size; (void)ws_size;
    const float* init_states    = (const float*)d_in[0];
    const float* future_states  = (const float*)d_in[1];
    const float* time_flags     = (const float*)d_in[2];
    const float* shortcut_value = (const float*)d_in[3];
    const float* input_w        = (const float*)d_in[4];
    const float* input_b        = (const float*)d_in[5];
    const float* states_emb     = (const float*)d_in[6];
    const float* time_w         = (const float*)d_in[7];
    const float* time_b         = (const float*)d_in[8];
    const float* short_w        = (const float*)d_in[9];
    const float* short_b        = (const float*)d_in[10];
    const float* in_proj_w      = (const float*)d_in[11];
    const float* conv_w         = (const float*)d_in[12];
    const float* conv_b         = (const float*)d_in[13];
    const float* dt_bias        = (const float*)d_in[14];
    const float* A_log          = (const float*)d_in[15];
    const float* D_skip         = (const float*)d_in[16];
    const float* mixer_norm_w   = (const float*)d_in[17];
    const float* out_proj_w     = (const float*)d_in[18];
    const float* layer_norm_w   = (const float*)d_in[19];
    const float* output_w       = (const float*)d_in[20];
    const float* output_b       = (const float*)d_in[21];
    float* ws = (float*)d_ws;
    float* outp = (float*)d_out;

    prep_weights<<<(WS_TOTAL + 255) / 256, 256, 0, stream>>>(
        in_proj_w, out_proj_w, mixer_norm_w, input_w, output_w, ws);
    mamba_all<<<BATCH, 256, 0, stream>>>(
        init_states, future_states, time_flags, shortcut_value,
        input_b, states_emb, time_w, time_b, short_w, short_b,
        conv_w, conv_b, dt_bias, A_log, D_skip, layer_norm_w,
        output_b, ws, outp);
}